// Round 3
// baseline (627.967 us; speedup 1.0000x reference)
//
#include <hip/hip_runtime.h>

#define NPTS 65536          // B*N = 32*2048
#define HH 256
#define DIN 131
#define LAT 128
#define STEPS 5
#define DT 0.2f
#define P 32                // points per block

typedef unsigned int uint;
typedef unsigned short ushort;
typedef __attribute__((ext_vector_type(8))) short short8;
typedef __attribute__((ext_vector_type(4))) float floatx4;

__device__ __forceinline__ float tanh_fast(float x) {
    // tanh(x) = 1 - 2/(exp2(2x*log2e)+1); exact at both saturated ends.
    float e = __builtin_amdgcn_exp2f(x * 2.8853900817779268f);
    return 1.0f - 2.0f * __builtin_amdgcn_rcpf(e + 1.0f);
}

__device__ __forceinline__ ushort f2bf(float f) {
    uint u = __builtin_bit_cast(uint, f);
    u += 0x7fffu + ((u >> 16) & 1u);   // RNE
    return (ushort)(u >> 16);
}

// pack two f32 -> 2x bf16 (RNE) in one instruction; lo -> bits[15:0]
__device__ __forceinline__ uint cvt_pk_bf16(float lo, float hi) {
    uint r;
    asm("v_cvt_pk_bf16_f32 %0, %1, %2" : "=v"(r) : "v"(lo), "v"(hi));
    return r;
}

// 16-lane row sum via DPP row_shr chain (VALU pipe, no LDS traffic).
// Result valid in lane 15 of each 16-lane row.
__device__ __forceinline__ float dpp_sum16(float x) {
    int t;
    t = __builtin_amdgcn_update_dpp(0, __builtin_bit_cast(int, x), 0x111, 0xf, 0xf, true);
    x += __builtin_bit_cast(float, t);
    t = __builtin_amdgcn_update_dpp(0, __builtin_bit_cast(int, x), 0x112, 0xf, 0xf, true);
    x += __builtin_bit_cast(float, t);
    t = __builtin_amdgcn_update_dpp(0, __builtin_bit_cast(int, x), 0x114, 0xf, 0xf, true);
    x += __builtin_bit_cast(float, t);
    t = __builtin_amdgcn_update_dpp(0, __builtin_bit_cast(int, x), 0x118, 0xf, 0xf, true);
    x += __builtin_bit_cast(float, t);
    return x;
}

// ---- prep:
//  a1t[s][b][h] = b1[h] + sum_l z[b][l]*W1[h][3+l] + W1[h][2]*(s*DT)
//  rs[h] = sum_l W1[h][3+l]
//  wsw[v] = bf16 B-fragments of (v==0 ? W2 : W2*diag(W1[:,v-1])):
//    wsw[v*65536 + ((nt*8+kt)*64+lane)*8+j] = W2[n][k+j] * (v? W1[k+j][v-1] : 1)
//    with n = nt*16+(lane&15), k = kt*32+(lane>>4)*8
__global__ void prep_kernel(const float* __restrict__ z, const float* __restrict__ W1,
                            const float* __restrict__ b1, const float* __restrict__ W2,
                            float* __restrict__ a1t, float* __restrict__ rsv,
                            ushort* __restrict__ wsw)
{
    int tid = blockIdx.x * 256 + threadIdx.x;
    if (tid < 8192) {
        int b = tid >> 8, h = tid & 255;
        const float* wrow = W1 + h * DIN;
        const float* zb = z + b * LAT;
        float s = b1[h], r = 0.f;
        #pragma unroll 4
        for (int l = 0; l < LAT; ++l) { float wv = wrow[3 + l]; s += wv * zb[l]; r += wv; }
        float wt = wrow[2];
        #pragma unroll
        for (int st = 0; st < STEPS; ++st)
            a1t[st * 8192 + tid] = s + wt * ((float)st * DT);
        if (b == 0) rsv[h] = r;
    } else {
        int t = tid - 8192;                    // 0..24575
        int v = t >> 13, tt = t & 8191;
        int lane = tt & 63, kt = (tt >> 6) & 7, nt = tt >> 9;
        int n = nt * 16 + (lane & 15);
        int k = kt * 32 + (lane >> 4) * 8;
        const float* src = W2 + n * HH + k;
        ushort* dst = wsw + v * 65536 + tt * 8;
        #pragma unroll
        for (int j = 0; j < 8; ++j) {
            float wv = src[j];
            if (v) wv *= W1[(k + j) * DIN + (v - 1)];
            dst[j] = f2bf(wv);
        }
    }
}

// V layout (swizzled, no padding): byte(v,p,h-pair hp) = v*16384 + p*512 + ((4*hp) ^ ((p&7)<<4))
// rows are 512B (bank-aligned); reads use the identical XOR so it is a pure relabeling.
// V0 = h1, V1 = g1.  Tangent GEMMs use pre-scaled B (wsw variants), so only 2 A-matrices.
__global__ __launch_bounds__(256, 2) void cnf_kernel(
        const float* __restrict__ xin, const float* __restrict__ W1,
        const float* __restrict__ b2, const float* __restrict__ W3,
        const float* __restrict__ b3, const float* __restrict__ osc,
        const float* __restrict__ a1t, const float* __restrict__ rsv,
        const ushort* __restrict__ wsw, float* __restrict__ out)
{
    __shared__ __align__(16) ushort Vb[2 * P * HH];          // 32768 B
    __shared__ float sums[4][P][3];                          // 1536 B (NOT aliased: inter-wave safety)
    __shared__ float wx0s[HH], wx1s[HH], rsS[HH];            // 3072 B
    __shared__ __align__(16) float4 XC[P];                   // 512 B: (x0, x1, c, -)

    const int tid = threadIdx.x;
    const int lane = tid & 63;
    const int w = tid >> 6;
    const int r15 = lane & 15;
    const int q = lane >> 4;
    const int blk = blockIdx.x;
    const int b = blk >> 6;                                  // 64 blocks per batch
    const int pbase = blk * P;
    const int hp = tid & 127;
    const int h0 = hp * 2;
    const int pst = tid >> 7;

    if (tid < HH) {
        wx0s[tid] = W1[tid * DIN + 0];
        wx1s[tid] = W1[tid * DIN + 1];
        rsS[tid]  = rsv[tid];
    }
    if (tid < P) {
        int gp = pbase + tid;
        XC[tid] = (float4){xin[gp * 2 + 0], xin[gp * 2 + 1], 0.f, 0.f};
    }
    const float os = osc[0];
    const float b30 = b3[0], b31 = b3[1];
    float w30r[4], w31r[4], b2r[4];
    #pragma unroll
    for (int n = 0; n < 4; ++n) {
        int j = (w * 4 + n) * 16 + r15;                      // this lane's output column
        w30r[n] = W3[j];
        w31r[n] = W3[HH + j];
        b2r[n] = b2[j];
    }
    __syncthreads();

    const char* vrow = (const char*)Vb + r15 * 512;          // mt -> +8192, g1 -> +16384
    const int xr = (r15 & 7) << 4;

    for (int s = 0; s < STEPS; ++s) {
        // ---- phase 1: layer-1 (collapsed) + build bf16 h1/g1 matrices in LDS ----
        {
            const float2 bab = *(const float2*)(a1t + (s * 32 + b) * HH + h0);
            const float wa  = wx0s[h0], wbv = wx0s[h0 + 1];
            const float wc  = wx1s[h0], wd  = wx1s[h0 + 1];
            const float ra  = rsS[h0],  rb  = rsS[h0 + 1];
            #pragma unroll
            for (int i = 0; i < 16; ++i) {
                int p = pst + 2 * i;
                float4 xc = XC[p];                           // broadcast read
                float pa = bab.x + wa  * xc.x + wc * xc.y + ra * xc.z;
                float pb = bab.y + wbv * xc.x + wd * xc.y + rb * xc.z;
                float ha = tanh_fast(pa), hb = tanh_fast(pb);
                float ga = 1.f - ha * ha, gb = 1.f - hb * hb;
                char* dst = (char*)Vb + p * 512 + ((4 * hp) ^ ((p & 7) << 4));
                *(uint*)(dst)         = cvt_pk_bf16(ha, hb);
                *(uint*)(dst + 16384) = cvt_pk_bf16(ga, gb);
            }
        }
        __syncthreads();

        // ---- GEMM in 2 N-passes: R0 = h1@W2^T, R1 = g1@W2d0^T, R2 = g1@W2d1^T ----
        float sv0[2][4], sv1[2][4], sdv[2][4];
        #pragma unroll
        for (int mt = 0; mt < 2; ++mt)
            #pragma unroll
            for (int r = 0; r < 4; ++r) {
                sv0[mt][r] = 0.f; sv1[mt][r] = 0.f; sdv[mt][r] = 0.f;
            }

        #pragma unroll
        for (int ph = 0; ph < 2; ++ph) {
            floatx4 acc[3][2][2];
            #pragma unroll
            for (int v = 0; v < 3; ++v)
                #pragma unroll
                for (int mt = 0; mt < 2; ++mt)
                    #pragma unroll
                    for (int n2 = 0; n2 < 2; ++n2)
                        acc[v][mt][n2] = (floatx4){0.f, 0.f, 0.f, 0.f};

            const ushort* wbp = wsw + (size_t)(w * 4 + ph * 2) * 4096 + (size_t)lane * 8;

            __builtin_amdgcn_s_setprio(1);
            #pragma unroll
            for (int kt = 0; kt < 8; ++kt) {
                const int boff = (kt * 64 + q * 16) ^ xr;    // swizzled K-slice byte offset
                const char* ap = vrow + boff;
                short8 ah[2], ag[2];
                #pragma unroll
                for (int mt = 0; mt < 2; ++mt) {
                    ah[mt] = *(const short8*)(ap + mt * 8192);
                    ag[mt] = *(const short8*)(ap + mt * 8192 + 16384);
                }
                #pragma unroll
                for (int n2 = 0; n2 < 2; ++n2) {
                    const ushort* bp = wbp + (size_t)(n2 * 8 + kt) * 512;
                    short8 bw  = *(const short8*)(bp);            // W2
                    short8 bd0 = *(const short8*)(bp + 65536);    // W2*diag(W1[:,0])
                    short8 bd1 = *(const short8*)(bp + 131072);   // W2*diag(W1[:,1])
                    #pragma unroll
                    for (int mt = 0; mt < 2; ++mt) {
                        acc[0][mt][n2] = __builtin_amdgcn_mfma_f32_16x16x32_bf16(ah[mt], bw,  acc[0][mt][n2], 0, 0, 0);
                        acc[1][mt][n2] = __builtin_amdgcn_mfma_f32_16x16x32_bf16(ag[mt], bd0, acc[1][mt][n2], 0, 0, 0);
                        acc[2][mt][n2] = __builtin_amdgcn_mfma_f32_16x16x32_bf16(ag[mt], bd1, acc[2][mt][n2], 0, 0, 0);
                    }
                }
            }
            __builtin_amdgcn_s_setprio(0);

            // ---- epilogue for this N-half: h2/g2, project with W3, accumulate ----
            #pragma unroll
            for (int mt = 0; mt < 2; ++mt)
                #pragma unroll
                for (int n2 = 0; n2 < 2; ++n2) {
                    const int n = ph * 2 + n2;
                    const float w0 = w30r[n], w1 = w31r[n], bbj = b2r[n];
                    #pragma unroll
                    for (int r = 0; r < 4; ++r) {
                        float h2 = tanh_fast(acc[0][mt][n2][r] + bbj);
                        float g2 = 1.f - h2 * h2;
                        sv0[mt][r] += h2 * w0;
                        sv1[mt][r] += h2 * w1;
                        sdv[mt][r] += g2 * (acc[1][mt][n2][r] * w0 + acc[2][mt][n2][r] * w1);
                    }
                }
        }

        // ---- reduce over the 16 j-lanes via DPP (VALU), stash per-wave sums ----
        #pragma unroll
        for (int mt = 0; mt < 2; ++mt)
            #pragma unroll
            for (int r = 0; r < 4; ++r) {
                float ta = dpp_sum16(sv0[mt][r]);
                float tb = dpp_sum16(sv1[mt][r]);
                float td = dpp_sum16(sdv[mt][r]);
                if (r15 == 15) {
                    int p = mt * 16 + q * 4 + r;
                    sums[w][p][0] = ta;
                    sums[w][p][1] = tb;
                    sums[w][p][2] = td;
                }
            }
        __syncthreads();

        // ---- state update (Euler), spread over 96 threads ----
        if (tid < 96) {
            int p = tid & 31, c = tid >> 5;
            float sv = sums[0][p][c] + sums[1][p][c] + sums[2][p][c] + sums[3][p][c];
            if (c == 0)      XC[p].x += (sv + b30) * os * DT;
            else if (c == 1) XC[p].y += (sv + b31) * os * DT;
            else             XC[p].z += sv * os * DT;
        }
        __syncthreads();
    }

    if (tid < P) {
        int gp = pbase + tid;
        float4 xc = XC[tid];
        out[gp * 2 + 0] = xc.x;
        out[gp * 2 + 1] = xc.y;
        out[NPTS * 2 + gp] = xc.z;        // log_det
    }
}

extern "C" void kernel_launch(void* const* d_in, const int* in_sizes, int n_in,
                              void* d_out, int out_size, void* d_ws, size_t ws_size,
                              hipStream_t stream) {
    const float* x   = (const float*)d_in[0];
    const float* z   = (const float*)d_in[1];
    const float* W1  = (const float*)d_in[2];
    const float* b1  = (const float*)d_in[3];
    const float* W2  = (const float*)d_in[4];
    const float* b2  = (const float*)d_in[5];
    const float* W3  = (const float*)d_in[6];
    const float* b3  = (const float*)d_in[7];
    const float* osc = (const float*)d_in[8];

    // ws layout: a1t [5*8192 f] @0 (160KB) | rs [256 f] @163840 | wsw [3*65536 bf16] @164864 (~545KB)
    float* a1t = (float*)d_ws;
    float* rsv = (float*)((char*)d_ws + 163840);
    ushort* wsw = (ushort*)((char*)d_ws + 164864);

    hipLaunchKernelGGL(prep_kernel, dim3(128), dim3(256), 0, stream, z, W1, b1, W2, a1t, rsv, wsw);
    hipLaunchKernelGGL(cnf_kernel, dim3(2048), dim3(256), 0, stream,
                       x, W1, b2, W3, b3, osc, a1t, rsv, wsw, (float*)d_out);
}

// Round 4
// 217.410 us; speedup vs baseline: 2.8884x; 2.8884x over previous
//
#include <hip/hip_runtime.h>

#define NPTS 65536          // B*N = 32*2048
#define HH 256
#define DIN 131
#define LAT 128
#define STEPS 5
#define DT 0.2f
#define P 32                // points per block

typedef unsigned int uint;
typedef unsigned short ushort;
typedef __attribute__((ext_vector_type(8))) short short8;
typedef __attribute__((ext_vector_type(4))) float floatx4;

__device__ __forceinline__ float tanh_fast(float x) {
    // tanh(x) = 1 - 2/(exp2(2x*log2e)+1); exact at both saturated ends.
    float e = __builtin_amdgcn_exp2f(x * 2.8853900817779268f);
    return 1.0f - 2.0f * __builtin_amdgcn_rcpf(e + 1.0f);
}

__device__ __forceinline__ ushort f2bf(float f) {
    uint u = __builtin_bit_cast(uint, f);
    u += 0x7fffu + ((u >> 16) & 1u);   // RNE
    return (ushort)(u >> 16);
}

// pack two f32 -> 2x bf16 (RNE) in one instruction; lo -> bits[15:0]
__device__ __forceinline__ uint cvt_pk_bf16(float lo, float hi) {
    uint r;
    asm("v_cvt_pk_bf16_f32 %0, %1, %2" : "=v"(r) : "v"(lo), "v"(hi));
    return r;
}

// 16-lane row sum via DPP row_shr chain (VALU pipe, no LDS traffic).
// Result valid in lane 15 of each 16-lane row. (Harness-verified in round 3.)
__device__ __forceinline__ float dpp_sum16(float x) {
    int t;
    t = __builtin_amdgcn_update_dpp(0, __builtin_bit_cast(int, x), 0x111, 0xf, 0xf, true);
    x += __builtin_bit_cast(float, t);
    t = __builtin_amdgcn_update_dpp(0, __builtin_bit_cast(int, x), 0x112, 0xf, 0xf, true);
    x += __builtin_bit_cast(float, t);
    t = __builtin_amdgcn_update_dpp(0, __builtin_bit_cast(int, x), 0x114, 0xf, 0xf, true);
    x += __builtin_bit_cast(float, t);
    t = __builtin_amdgcn_update_dpp(0, __builtin_bit_cast(int, x), 0x118, 0xf, 0xf, true);
    x += __builtin_bit_cast(float, t);
    return x;
}

// ---- prep:
//  a1t[s][b][h] = b1[h] + sum_l z[b][l]*W1[h][3+l] + W1[h][2]*(s*DT)   (time-bias folded per step)
//  rs[h] = sum_l W1[h][3+l]
//  wsw = W2 as bf16 B-fragments: wsw[((nt*8+kt)*64+lane)*8+j] = W2[nt*16+(lane&15)][kt*32+(lane>>4)*8+j]
__global__ void prep_kernel(const float* __restrict__ z, const float* __restrict__ W1,
                            const float* __restrict__ b1, const float* __restrict__ W2,
                            float* __restrict__ a1t, float* __restrict__ rsv,
                            ushort* __restrict__ wsw)
{
    int tid = blockIdx.x * 256 + threadIdx.x;
    if (tid < 8192) {
        int b = tid >> 8, h = tid & 255;
        const float* wrow = W1 + h * DIN;
        const float* zb = z + b * LAT;
        float s = b1[h], r = 0.f;
        for (int l = 0; l < LAT; ++l) { float wv = wrow[3 + l]; s += wv * zb[l]; r += wv; }
        float wt = wrow[2];
        #pragma unroll
        for (int st = 0; st < STEPS; ++st)
            a1t[st * 8192 + tid] = s + wt * ((float)st * DT);
        if (b == 0) rsv[h] = r;
    } else {
        int t = tid - 8192;                    // 0..8191
        int lane = t & 63, kt = (t >> 6) & 7, nt = t >> 9;
        int n = nt * 16 + (lane & 15);
        int k = kt * 32 + (lane >> 4) * 8;
        const float* src = W2 + n * HH + k;
        ushort* dst = wsw + t * 8;
        #pragma unroll
        for (int j = 0; j < 8; ++j) dst[j] = f2bf(src[j]);
    }
}

// V layout (swizzled, no padding): byte(v,p,h-pair hp) = v*16384 + p*512 + ((4*hp) ^ ((p&7)<<4))
// rows are 512B (bank-aligned); reads use the identical XOR so it is a pure relabeling.
// V0 = h1, V1 = g1*W1x0, V2 = g1*W1x1.  Single B-stream (W2 fragments from global/L2).
// LDS total = 49152 + 1536 + 512 = 51200 B -> 3 blocks/CU.
__global__ __launch_bounds__(256, 2) void cnf_kernel(
        const float* __restrict__ xin, const float* __restrict__ W1,
        const float* __restrict__ b2, const float* __restrict__ W3,
        const float* __restrict__ b3, const float* __restrict__ osc,
        const float* __restrict__ a1t, const float* __restrict__ rsv,
        const ushort* __restrict__ wsw, float* __restrict__ out)
{
    __shared__ __align__(16) ushort Vb[3 * P * HH];          // 49152 B
    __shared__ float sums[4][P][3];                          // 1536 B (not aliased)
    __shared__ __align__(16) float4 XC[P];                   // 512 B: (x0, x1, c, -)

    const int tid = threadIdx.x;
    const int lane = tid & 63;
    const int w = tid >> 6;
    const int r15 = lane & 15;
    const int q = lane >> 4;
    const int blk = blockIdx.x;
    const int b = blk >> 6;                                  // 64 blocks per batch
    const int pbase = blk * P;
    const int hp = tid & 127;
    const int h0 = hp * 2;
    const int pst = tid >> 7;

    // per-thread layer-1 constants (own h-pair only; replaces 3KB of LDS tables)
    const float wa  = W1[h0 * DIN + 0],  wbv = W1[(h0 + 1) * DIN + 0];
    const float wc  = W1[h0 * DIN + 1],  wd  = W1[(h0 + 1) * DIN + 1];
    const float ra  = rsv[h0],           rb  = rsv[h0 + 1];

    if (tid < P) {
        int gp = pbase + tid;
        XC[tid] = (float4){xin[gp * 2 + 0], xin[gp * 2 + 1], 0.f, 0.f};
    }
    const float os = osc[0];
    const float b30 = b3[0], b31 = b3[1];
    float w30r[4], w31r[4], b2r[4];
    #pragma unroll
    for (int n = 0; n < 4; ++n) {
        int j = (w * 4 + n) * 16 + r15;                      // this lane's output column
        w30r[n] = W3[j];
        w31r[n] = W3[HH + j];
        b2r[n] = b2[j];
    }
    __syncthreads();

    const char* vrow = (const char*)Vb + r15 * 512;          // mt -> +8192, v -> +16384
    const int xr = (r15 & 7) << 4;

    for (int s = 0; s < STEPS; ++s) {
        // ---- phase 1: layer-1 (collapsed) + build bf16 A-matrices in LDS ----
        {
            const float2 bab = *(const float2*)(a1t + (s * 32 + b) * HH + h0);
            #pragma unroll
            for (int i = 0; i < 16; ++i) {
                int p = pst + 2 * i;
                float4 xc = XC[p];                           // broadcast read
                float pa = bab.x + wa  * xc.x + wc * xc.y + ra * xc.z;
                float pb = bab.y + wbv * xc.x + wd * xc.y + rb * xc.z;
                float ha = tanh_fast(pa), hb = tanh_fast(pb);
                float ga = 1.f - ha * ha, gb = 1.f - hb * hb;
                char* dst = (char*)Vb + p * 512 + ((4 * hp) ^ ((p & 7) << 4));
                *(uint*)(dst)         = cvt_pk_bf16(ha,       hb);
                *(uint*)(dst + 16384) = cvt_pk_bf16(ga * wa,  gb * wbv);
                *(uint*)(dst + 32768) = cvt_pk_bf16(ga * wc,  gb * wd);
            }
        }
        __syncthreads();

        // ---- GEMM in 2 N-passes (acc = 48 VGPRs; B not duplicated) ----
        float sv0[2][4], sv1[2][4], sdv[2][4];
        #pragma unroll
        for (int mt = 0; mt < 2; ++mt)
            #pragma unroll
            for (int r = 0; r < 4; ++r) {
                sv0[mt][r] = 0.f; sv1[mt][r] = 0.f; sdv[mt][r] = 0.f;
            }

        #pragma unroll
        for (int ph = 0; ph < 2; ++ph) {
            floatx4 acc[3][2][2];
            #pragma unroll
            for (int v = 0; v < 3; ++v)
                #pragma unroll
                for (int mt = 0; mt < 2; ++mt)
                    #pragma unroll
                    for (int n2 = 0; n2 < 2; ++n2)
                        acc[v][mt][n2] = (floatx4){0.f, 0.f, 0.f, 0.f};

            const ushort* wbp = wsw + (size_t)(w * 4 + ph * 2) * 4096 + (size_t)lane * 8;

            __builtin_amdgcn_s_setprio(1);
            #pragma unroll
            for (int kt = 0; kt < 8; ++kt) {
                const int boff = (kt * 64 + q * 16) ^ xr;    // swizzled K-slice byte offset
                short8 bf0 = *(const short8*)(wbp + (size_t)(kt) * 512);
                short8 bf1 = *(const short8*)(wbp + (size_t)(8 + kt) * 512);
                #pragma unroll
                for (int mt = 0; mt < 2; ++mt) {
                    const char* ap = vrow + mt * 8192 + boff;
                    short8 a0f = *(const short8*)(ap);
                    short8 a1f = *(const short8*)(ap + 16384);
                    short8 a2f = *(const short8*)(ap + 32768);
                    acc[0][mt][0] = __builtin_amdgcn_mfma_f32_16x16x32_bf16(a0f, bf0, acc[0][mt][0], 0, 0, 0);
                    acc[1][mt][0] = __builtin_amdgcn_mfma_f32_16x16x32_bf16(a1f, bf0, acc[1][mt][0], 0, 0, 0);
                    acc[2][mt][0] = __builtin_amdgcn_mfma_f32_16x16x32_bf16(a2f, bf0, acc[2][mt][0], 0, 0, 0);
                    acc[0][mt][1] = __builtin_amdgcn_mfma_f32_16x16x32_bf16(a0f, bf1, acc[0][mt][1], 0, 0, 0);
                    acc[1][mt][1] = __builtin_amdgcn_mfma_f32_16x16x32_bf16(a1f, bf1, acc[1][mt][1], 0, 0, 0);
                    acc[2][mt][1] = __builtin_amdgcn_mfma_f32_16x16x32_bf16(a2f, bf1, acc[2][mt][1], 0, 0, 0);
                }
            }
            __builtin_amdgcn_s_setprio(0);

            // ---- epilogue for this N-half: h2/g2, project with W3, accumulate ----
            #pragma unroll
            for (int mt = 0; mt < 2; ++mt)
                #pragma unroll
                for (int n2 = 0; n2 < 2; ++n2) {
                    const int n = ph * 2 + n2;
                    const float w0 = w30r[n], w1 = w31r[n], bbj = b2r[n];
                    #pragma unroll
                    for (int r = 0; r < 4; ++r) {
                        float h2 = tanh_fast(acc[0][mt][n2][r] + bbj);
                        float g2 = 1.f - h2 * h2;
                        sv0[mt][r] += h2 * w0;
                        sv1[mt][r] += h2 * w1;
                        sdv[mt][r] += g2 * (acc[1][mt][n2][r] * w0 + acc[2][mt][n2][r] * w1);
                    }
                }
        }

        // ---- reduce over the 16 j-lanes via DPP (VALU pipe), stash per-wave sums ----
        #pragma unroll
        for (int mt = 0; mt < 2; ++mt)
            #pragma unroll
            for (int r = 0; r < 4; ++r) {
                float ta = dpp_sum16(sv0[mt][r]);
                float tb = dpp_sum16(sv1[mt][r]);
                float td = dpp_sum16(sdv[mt][r]);
                if (r15 == 15) {
                    int p = mt * 16 + q * 4 + r;
                    sums[w][p][0] = ta;
                    sums[w][p][1] = tb;
                    sums[w][p][2] = td;
                }
            }
        __syncthreads();

        // ---- state update (Euler), spread over 96 threads ----
        if (tid < 96) {
            int p = tid & 31, c = tid >> 5;
            float sv = sums[0][p][c] + sums[1][p][c] + sums[2][p][c] + sums[3][p][c];
            if (c == 0)      XC[p].x += (sv + b30) * os * DT;
            else if (c == 1) XC[p].y += (sv + b31) * os * DT;
            else             XC[p].z += sv * os * DT;
        }
        __syncthreads();
    }

    if (tid < P) {
        int gp = pbase + tid;
        float4 xc = XC[tid];
        out[gp * 2 + 0] = xc.x;
        out[gp * 2 + 1] = xc.y;
        out[NPTS * 2 + gp] = xc.z;        // log_det
    }
}

extern "C" void kernel_launch(void* const* d_in, const int* in_sizes, int n_in,
                              void* d_out, int out_size, void* d_ws, size_t ws_size,
                              hipStream_t stream) {
    const float* x   = (const float*)d_in[0];
    const float* z   = (const float*)d_in[1];
    const float* W1  = (const float*)d_in[2];
    const float* b1  = (const float*)d_in[3];
    const float* W2  = (const float*)d_in[4];
    const float* b2  = (const float*)d_in[5];
    const float* W3  = (const float*)d_in[6];
    const float* b3  = (const float*)d_in[7];
    const float* osc = (const float*)d_in[8];

    // ws layout: a1t [5*8192 f] @0 (160KB) | rs [256 f] @163840 | wsw [65536 bf16] @164864 (~289KB)
    float* a1t = (float*)d_ws;
    float* rsv = (float*)((char*)d_ws + 163840);
    ushort* wsw = (ushort*)((char*)d_ws + 164864);

    hipLaunchKernelGGL(prep_kernel, dim3(64), dim3(256), 0, stream, z, W1, b1, W2, a1t, rsv, wsw);
    hipLaunchKernelGGL(cnf_kernel, dim3(2048), dim3(256), 0, stream,
                       x, W1, b2, W3, b3, osc, a1t, rsv, wsw, (float*)d_out);
}